// Round 15
// baseline (140.768 us; speedup 1.0000x reference)
//
#include <hip/hip_runtime.h>
#include <math.h>

#define N_EMBED 8192
#define DIM 32
#define NQ 32768              // 32*32*32 queries

#define QPB 512               // queries per block (8 waves x 64) — R16 proven best
#define NQG (NQ / QPB)        // 64 query groups
#define KSPL 8                // keys16 2MiB; grid 512 = 2 blocks/CU
#define KCHUNK (N_EMBED / KSPL)   // 1024 codes per block
#define TILE 128              // codes per LDS tile
#define NTILES (KCHUNK / TILE)    // 8
#define NPLANE 8              // p = part (h), 4+part (m')
#define LSTRIDE 130           // half8 per plane (+2 pad: planes offset 8 banks)

#define LOSS_OFF  1048576
#define ENT_OFF   1048577
#define IDX_OFF   1048578

typedef __attribute__((ext_vector_type(8))) _Float16 half8;
typedef __attribute__((ext_vector_type(4))) float floatx4;

// ---------------------------------------------------------------------------
// K0: prep — normalize+split the codebook ONCE into a tile-plane-major fp16
// image (1 MiB). Zeroes usage/loss/done_ctr. (R20: + done_ctr for the merged
// finalize scalar pass.)
// ---------------------------------------------------------------------------
__global__ __launch_bounds__(256) void prep_kernel(const float* __restrict__ e,
                                                   half8* __restrict__ prep,
                                                   unsigned* __restrict__ usage,
                                                   float* __restrict__ loss_acc,
                                                   unsigned* __restrict__ done_ctr) {
    const int t = threadIdx.x;
    if (blockIdx.x == 0) {
        for (int i = t; i < N_EMBED; i += 256)
            __hip_atomic_store(&usage[i], 0u, __ATOMIC_RELAXED, __HIP_MEMORY_SCOPE_AGENT);
        if (t == 0) {
            __hip_atomic_store(loss_acc, 0.f, __ATOMIC_RELAXED, __HIP_MEMORY_SCOPE_AGENT);
            __hip_atomic_store(done_ctr, 0u, __ATOMIC_RELAXED, __HIP_MEMORY_SCOPE_AGENT);
        }
    }

    const int g = blockIdx.x * 256 + t;       // 0..32767
    const int code = g >> 2;
    const int part = g & 3;                   // == lane&3 (4-lane groups aligned)

    const float4* er = (const float4*)(e + code * DIM) + part * 2;
    float4 v0 = er[0], v1 = er[1];
    float x[8] = {v0.x, v0.y, v0.z, v0.w, v1.x, v1.y, v1.z, v1.w};
    float ss = 0.f;
#pragma unroll
    for (int j = 0; j < 8; ++j) ss = fmaf(x[j], x[j], ss);
    ss += __shfl_xor(ss, 1, 64);
    ss += __shfl_xor(ss, 2, 64);
    float inv = 1.f / fmaxf(sqrtf(ss), 1e-12f);
    half8 h8, m8;
#pragma unroll
    for (int j = 0; j < 8; ++j) {
        float xx = x[j] * inv;
        _Float16 h = (_Float16)xx;                           // RNE
        _Float16 m = (_Float16)((xx - (float)h) * 4096.0f);  // exact residual
        h8[j] = h; m8[j] = m;
    }
    const int kc = code >> 10, cc = code & 1023;
    const int kt = cc >> 7,   ci = cc & 127;
    const int pb = (kc * NTILES + kt) * NPLANE;
    prep[(pb + part) * 128 + ci]     = h8;
    prep[(pb + 4 + part) * 128 + ci] = m8;
}

// ---------------------------------------------------------------------------
// K1: split-fp16 MFMA scorer — R16 byte-exact (best proven: 58.2us).
// Issue-bound diagnosis (R19): VALUBusy+MfmaUtil ~= 90-97% across all 4
// structural variants (16w/32w x LDS/cache), all converge at 58-60us.
// Score is parked here; this round cuts dispatch count.
// ---------------------------------------------------------------------------
__global__ __launch_bounds__(512, 4) void score_kernel(const float* __restrict__ z,
                                                       const half8* __restrict__ prep,
                                                       unsigned long long* __restrict__ keys16) {
    __shared__ half8 lds[2][NPLANE * LSTRIDE];   // 33,280 B

    const int t = threadIdx.x;
    const int lane = t & 63;
    const int w = t >> 6;            // wave 0..7
    const int quad = lane >> 4;      // k-group / C-row group
    const int lc = lane & 15;        // A-row / B-col / C-col
    const int qg = blockIdx.x & (NQG - 1);
    const int kc = blockIdx.x >> 6;          // 0..KSPL-1
    const int kbase = kc * KCHUNK;
    const int qbase = qg * QPB + w * 64;

    // ---- A fragments: 4 q-tiles of 16 rows, normalize + fp16 split ----
    half8 ah4[4], ah[4], am[4];
#pragma unroll
    for (int qt = 0; qt < 4; ++qt) {
        int q = qbase + qt * 16 + lc;
        const float* zp = z + (q >> 10) * (DIM * 1024) + (q & 1023);
        float x[8];
        float ss = 0.f;
#pragma unroll
        for (int j = 0; j < 8; ++j) {
            x[j] = zp[(quad * 8 + j) * 1024];
            ss = fmaf(x[j], x[j], ss);
        }
        ss += __shfl_xor(ss, 16, 64);   // combine the 4 quads holding this query
        ss += __shfl_xor(ss, 32, 64);
        float inv = 1.f / fmaxf(sqrtf(ss), 1e-12f);
#pragma unroll
        for (int j = 0; j < 8; ++j) {
            float xx = x[j] * inv;
            _Float16 h = (_Float16)xx;
            _Float16 m = (_Float16)((xx - (float)h) * 4096.0f);
            ah[qt][j] = h;
            ah4[qt][j] = (_Float16)((float)h * 4096.0f);   // exact (exp shift)
            am[qt][j] = m;
        }
    }

    // ---- stage: pure DMA, wave w owns plane w (2 x 1KB per tile) ----
    const char* prepb = (const char*)prep;
    auto stage_dma = [&](int bsel, int kt) {
        const char* gsrc = prepb + ((size_t)((kc * NTILES + kt) * NPLANE + w)) * 2048
                                 + (size_t)lane * 16;
        char* lbase = (char*)&lds[bsel][w * LSTRIDE];      // wave-uniform
        __builtin_amdgcn_global_load_lds(
            (const __attribute__((address_space(1))) void*)(gsrc),
            (__attribute__((address_space(3))) void*)(lbase), 16, 0, 0);
        __builtin_amdgcn_global_load_lds(
            (const __attribute__((address_space(1))) void*)(gsrc + 1024),
            (__attribute__((address_space(3))) void*)(lbase + 1024), 16, 0, 0);
    };

    float best[16];
    int bk[16];
#pragma unroll
    for (int i = 0; i < 16; ++i) { best[i] = -9000.0f; bk[i] = 0; }   // scaled dots >= -4096

    const floatx4 z4 = {0.f, 0.f, 0.f, 0.f};

    stage_dma(0, 0);
    __syncthreads();                 // implicit vmcnt(0): tile 0 landed

    for (int kt = 0; kt < NTILES; ++kt) {
        if (kt + 1 < NTILES) stage_dma((kt + 1) & 1, kt + 1);   // DMA overlaps MFMAs

        const half8* __restrict__ buf = lds[kt & 1];
#pragma unroll 2
        for (int ct = 0; ct < TILE / 16; ++ct) {
            half8 bh = buf[(0 * 4 + quad) * LSTRIDE + ct * 16 + lc];
            half8 bm = buf[(1 * 4 + quad) * LSTRIDE + ct * 16 + lc];
            const int kk = kbase + kt * TILE + ct * 16 + lc;
#pragma unroll
            for (int qt = 0; qt < 4; ++qt) {
                floatx4 acc = __builtin_amdgcn_mfma_f32_16x16x32_f16(ah4[qt], bh, z4, 0, 0, 0);
                acc = __builtin_amdgcn_mfma_f32_16x16x32_f16(ah[qt], bm, acc, 0, 0, 0);
                acc = __builtin_amdgcn_mfma_f32_16x16x32_f16(am[qt], bh, acc, 0, 0, 0);
#pragma unroll
                for (int r = 0; r < 4; ++r) {
                    float d = acc[r];
                    if (d > best[qt * 4 + r]) { best[qt * 4 + r] = d; bk[qt * 4 + r] = kk; }
                }
            }
        }
        __syncthreads();   // drains DMA (vmcnt0) + frees computed buffer
    }

    // ---- epilogue: pack (scaled dot, k), reduce over 16 cols, coherent store ----
#pragma unroll
    for (int i = 0; i < 16; ++i) {
        unsigned ub = __float_as_uint(best[i]);
        ub = (ub & 0x80000000u) ? ~ub : (ub | 0x80000000u);
        unsigned long long key = ((unsigned long long)ub << 32) | (unsigned)(~bk[i]);
#pragma unroll
        for (int msk = 1; msk <= 8; msk <<= 1) {
            unsigned long long o = __shfl_xor(key, msk, 64);
            key = (o > key) ? o : key;
        }
        if (lc == 0) {
            int qt = i >> 2, r = i & 3;
            int q = qbase + qt * 16 + quad * 4 + r;   // C row = quad*4 + reg
            __hip_atomic_store(&keys16[kc * NQ + q], key,
                               __ATOMIC_RELAXED, __HIP_MEMORY_SCOPE_AGENT);
        }
    }
}

// ---------------------------------------------------------------------------
// K2: finalize + scalars merged (R20). Per-query work = R8's proven version.
// Scalar pass runs in the LAST-DONE block — fence-FREE: __syncthreads'
// implicit vmcnt(0) drains each block's usage/loss atomics to the coherent
// point before thread 0's ACQ_REL fetch_add(done_ctr); the last block's
// acquire + relaxed ATOMIC loads (bypass L1) then see all contributions.
// No __threadfence (R7's cost: device-writeback of 4MB out per block).
// Saves one dispatch vs the split version.
// ---------------------------------------------------------------------------
__global__ __launch_bounds__(128) void finalize_kernel(const float* __restrict__ z,
                                                       const float* __restrict__ e,
                                                       const unsigned long long* __restrict__ keys16,
                                                       unsigned* __restrict__ usage,
                                                       float* __restrict__ loss_acc,
                                                       unsigned* __restrict__ done_ctr,
                                                       float* __restrict__ out) {
    int n = blockIdx.x * 128 + threadIdx.x;        // 0..NQ-1
    int b  = n >> 10;
    int hw = n & 1023;
    const float* zb = z + b * (DIM * 1024) + hw;

    float q[DIM];
    float ss = 0.f;
#pragma unroll
    for (int d = 0; d < DIM; ++d) {
        q[d] = zb[d * 1024];
        ss = fmaf(q[d], q[d], ss);
    }
    float inv = 1.f / fmaxf(sqrtf(ss), 1e-12f);
#pragma unroll
    for (int d = 0; d < DIM; ++d) q[d] *= inv;

    unsigned long long bestkey = 0ull;
#pragma unroll
    for (int c = 0; c < KSPL; ++c) {
        unsigned long long k16 = __hip_atomic_load(&keys16[c * NQ + n],
                                                   __ATOMIC_RELAXED,
                                                   __HIP_MEMORY_SCOPE_AGENT);
        bestkey = (k16 > bestkey) ? k16 : bestkey;
    }
    int idx = (int)(~(unsigned)(bestkey & 0xFFFFFFFFull));

    atomicAdd(&usage[idx], 1u);

    // gather winner row, normalize locally, write straight-through + loss
    float wv[DIM];
    float ss2 = 0.f;
    const float4* er = (const float4*)(e + idx * DIM);
#pragma unroll
    for (int d8 = 0; d8 < 8; ++d8) {
        float4 t4 = er[d8];
        wv[d8*4+0] = t4.x; wv[d8*4+1] = t4.y; wv[d8*4+2] = t4.z; wv[d8*4+3] = t4.w;
        ss2 += t4.x*t4.x + t4.y*t4.y + t4.z*t4.z + t4.w*t4.w;
    }
    float inv2 = 1.f / fmaxf(sqrtf(ss2), 1e-12f);

    float lsum = 0.f;
    float* outb = out + b * (DIM * 1024) + hw;
#pragma unroll
    for (int d = 0; d < DIM; ++d) {
        float zq = wv[d] * inv2;
        float diff = zq - q[d];
        lsum = fmaf(diff, diff, lsum);
        outb[d * 1024] = q[d] + (zq - q[d]);   // faithful to zn + sg(z_q - zn)
    }
    out[IDX_OFF + n] = (float)idx;

    // block-level loss reduction: wave shfl -> LDS -> one atomic per block
#pragma unroll
    for (int off = 32; off > 0; off >>= 1)
        lsum += __shfl_down(lsum, off, 64);
    __shared__ float wsum[2];
    if ((threadIdx.x & 63) == 0) wsum[threadIdx.x >> 6] = lsum;
    __syncthreads();
    if (threadIdx.x == 0)
        atomicAdd(loss_acc, wsum[0] + wsum[1]);

    // ---- last-done block computes the scalars (fence-free) ----
    __shared__ unsigned lastflag;
    __syncthreads();                 // drains this block's atomics (vmcnt 0)
    if (threadIdx.x == 0) {
        unsigned prev = __hip_atomic_fetch_add(done_ctr, 1u, __ATOMIC_ACQ_REL,
                                               __HIP_MEMORY_SCOPE_AGENT);
        lastflag = (prev == gridDim.x - 1) ? 1u : 0u;
    }
    __syncthreads();
    if (lastflag) {
        __shared__ double sm[128];
        int t = threadIdx.x;
        double local = 0.0;
        const float denom = 32768.8192f;   // sum(usage)+K*eps; sum(usage)==NQ
        for (int k = t; k < N_EMBED; k += 128) {
            unsigned c = __hip_atomic_load(&usage[k], __ATOMIC_RELAXED,
                                           __HIP_MEMORY_SCOPE_AGENT);
            float p = ((float)c + 1e-4f) / denom;
            local += (double)(-(p * logf(p)));
        }
        sm[t] = local;
        __syncthreads();
        for (int s = 64; s > 0; s >>= 1) {
            if (t < s) sm[t] += sm[t + s];
            __syncthreads();
        }
        if (t == 0) {
            float la = __hip_atomic_load(loss_acc, __ATOMIC_RELAXED,
                                         __HIP_MEMORY_SCOPE_AGENT);
            out[LOSS_OFF] = (float)(1.25 * (double)la / 32768.0);  // (beta+1)*mean
            out[ENT_OFF]  = (float)sm[0];
        }
    }
}

// ---------------------------------------------------------------------------
extern "C" void kernel_launch(void* const* d_in, const int* in_sizes, int n_in,
                              void* d_out, int out_size, void* d_ws, size_t ws_size,
                              hipStream_t stream) {
    const float* z   = (const float*)d_in[0];   // (32, 32, 32, 32) bchw
    const float* emb = (const float*)d_in[1];   // (8192, 32)
    float* out = (float*)d_out;

    char* ws = (char*)d_ws;
    unsigned long long* keys16 = (unsigned long long*)ws;                    // 2 MiB @ 0
    half8* prep                = (half8*)(ws + (2 << 20));                   // 1 MiB
    unsigned* usage            = (unsigned*)(ws + (3 << 20));                // 32 KiB
    float* loss_acc            = (float*)(ws + (3 << 20) + 32768);
    unsigned* done_ctr         = (unsigned*)(ws + (3 << 20) + 32768 + 4);

    prep_kernel<<<(N_EMBED * 4) / 256, 256, 0, stream>>>(emb, prep, usage,
                                                         loss_acc, done_ctr);
    score_kernel<<<NQG * KSPL, 512, 0, stream>>>(z, prep, keys16);
    finalize_kernel<<<NQ / 128, 128, 0, stream>>>(z, emb, keys16, usage,
                                                  loss_acc, done_ctr, out);
}

// Round 16
// 128.592 us; speedup vs baseline: 1.0947x; 1.0947x over previous
//
#include <hip/hip_runtime.h>
#include <math.h>

#define N_EMBED 8192
#define DIM 32
#define NQ 32768              // 32*32*32 queries

#define QPB 512               // queries per block (8 waves x 64)
#define NQG (NQ / QPB)        // 64 query groups
#define KSPL 8                // keys16 2MiB; grid 512 = 2 blocks/CU
#define KCHUNK (N_EMBED / KSPL)   // 1024 codes per block
#define TILE 128              // codes per LDS tile
#define NTILES (KCHUNK / TILE)    // 8
#define NPLANE 8              // p = part (h), 4+part (m')
#define LSTRIDE 130           // half8 per plane (+2 pad: planes offset 8 banks)

#define LOSS_OFF  1048576
#define ENT_OFF   1048577
#define IDX_OFF   1048578

typedef __attribute__((ext_vector_type(8))) _Float16 half8;
typedef __attribute__((ext_vector_type(4))) float floatx4;

// ---------------------------------------------------------------------------
// R21 = EXACT revert to the R16 state (best measured: 129.3us total).
// R20's merged finalize+scalar regressed 11us — replicating R7->R8 from the
// other direction: in-kernel last-block completion (256 serialized ACQ_REL
// RMWs + 2 extra barriers/block) costs more than one small dispatch.
// Session ledger: score issue-bound at 57-58us (VALUBusy+MfmaUtil ~92%,
// 4 structural variants converge); finalize structure optimal of 4 tested;
// residual ~62us non-score time is fixed harness overhead.
// ---------------------------------------------------------------------------

// K0: prep — normalize+split codebook ONCE into tile-plane-major fp16 image
// (1 MiB). Zeroes usage/loss.
__global__ __launch_bounds__(256) void prep_kernel(const float* __restrict__ e,
                                                   half8* __restrict__ prep,
                                                   unsigned* __restrict__ usage,
                                                   float* __restrict__ loss_acc) {
    const int t = threadIdx.x;
    if (blockIdx.x == 0) {
        for (int i = t; i < N_EMBED; i += 256)
            __hip_atomic_store(&usage[i], 0u, __ATOMIC_RELAXED, __HIP_MEMORY_SCOPE_AGENT);
        if (t == 0)
            __hip_atomic_store(loss_acc, 0.f, __ATOMIC_RELAXED, __HIP_MEMORY_SCOPE_AGENT);
    }

    const int g = blockIdx.x * 256 + t;       // 0..32767
    const int code = g >> 2;
    const int part = g & 3;                   // == lane&3 (4-lane groups aligned)

    const float4* er = (const float4*)(e + code * DIM) + part * 2;
    float4 v0 = er[0], v1 = er[1];
    float x[8] = {v0.x, v0.y, v0.z, v0.w, v1.x, v1.y, v1.z, v1.w};
    float ss = 0.f;
#pragma unroll
    for (int j = 0; j < 8; ++j) ss = fmaf(x[j], x[j], ss);
    ss += __shfl_xor(ss, 1, 64);
    ss += __shfl_xor(ss, 2, 64);
    float inv = 1.f / fmaxf(sqrtf(ss), 1e-12f);
    half8 h8, m8;
#pragma unroll
    for (int j = 0; j < 8; ++j) {
        float xx = x[j] * inv;
        _Float16 h = (_Float16)xx;                           // RNE
        _Float16 m = (_Float16)((xx - (float)h) * 4096.0f);  // exact residual
        h8[j] = h; m8[j] = m;
    }
    const int kc = code >> 10, cc = code & 1023;
    const int kt = cc >> 7,   ci = cc & 127;
    const int pb = (kc * NTILES + kt) * NPLANE;
    prep[(pb + part) * 128 + ci]     = h8;
    prep[(pb + 4 + part) * 128 + ci] = m8;
}

// K1: split-fp16 MFMA scorer, 16x16x32, single-acc: acc = 4096*dot =
// 4096*hh + h*m' + m'*h (ah4 pre-scaled exact). LDS-DMA staging.
__global__ __launch_bounds__(512, 4) void score_kernel(const float* __restrict__ z,
                                                       const half8* __restrict__ prep,
                                                       unsigned long long* __restrict__ keys16) {
    __shared__ half8 lds[2][NPLANE * LSTRIDE];   // 33,280 B

    const int t = threadIdx.x;
    const int lane = t & 63;
    const int w = t >> 6;            // wave 0..7
    const int quad = lane >> 4;      // k-group / C-row group
    const int lc = lane & 15;        // A-row / B-col / C-col
    const int qg = blockIdx.x & (NQG - 1);
    const int kc = blockIdx.x >> 6;          // 0..KSPL-1
    const int kbase = kc * KCHUNK;
    const int qbase = qg * QPB + w * 64;

    // ---- A fragments: 4 q-tiles of 16 rows, normalize + fp16 split ----
    half8 ah4[4], ah[4], am[4];
#pragma unroll
    for (int qt = 0; qt < 4; ++qt) {
        int q = qbase + qt * 16 + lc;
        const float* zp = z + (q >> 10) * (DIM * 1024) + (q & 1023);
        float x[8];
        float ss = 0.f;
#pragma unroll
        for (int j = 0; j < 8; ++j) {
            x[j] = zp[(quad * 8 + j) * 1024];
            ss = fmaf(x[j], x[j], ss);
        }
        ss += __shfl_xor(ss, 16, 64);   // combine the 4 quads holding this query
        ss += __shfl_xor(ss, 32, 64);
        float inv = 1.f / fmaxf(sqrtf(ss), 1e-12f);
#pragma unroll
        for (int j = 0; j < 8; ++j) {
            float xx = x[j] * inv;
            _Float16 h = (_Float16)xx;
            _Float16 m = (_Float16)((xx - (float)h) * 4096.0f);
            ah[qt][j] = h;
            ah4[qt][j] = (_Float16)((float)h * 4096.0f);   // exact (exp shift)
            am[qt][j] = m;
        }
    }

    // ---- stage: pure DMA, wave w owns plane w (2 x 1KB per tile) ----
    const char* prepb = (const char*)prep;
    auto stage_dma = [&](int bsel, int kt) {
        const char* gsrc = prepb + ((size_t)((kc * NTILES + kt) * NPLANE + w)) * 2048
                                 + (size_t)lane * 16;
        char* lbase = (char*)&lds[bsel][w * LSTRIDE];      // wave-uniform
        __builtin_amdgcn_global_load_lds(
            (const __attribute__((address_space(1))) void*)(gsrc),
            (__attribute__((address_space(3))) void*)(lbase), 16, 0, 0);
        __builtin_amdgcn_global_load_lds(
            (const __attribute__((address_space(1))) void*)(gsrc + 1024),
            (__attribute__((address_space(3))) void*)(lbase + 1024), 16, 0, 0);
    };

    float best[16];
    int bk[16];
#pragma unroll
    for (int i = 0; i < 16; ++i) { best[i] = -9000.0f; bk[i] = 0; }   // scaled dots >= -4096

    const floatx4 z4 = {0.f, 0.f, 0.f, 0.f};

    stage_dma(0, 0);
    __syncthreads();                 // implicit vmcnt(0): tile 0 landed

    for (int kt = 0; kt < NTILES; ++kt) {
        if (kt + 1 < NTILES) stage_dma((kt + 1) & 1, kt + 1);   // DMA overlaps MFMAs

        const half8* __restrict__ buf = lds[kt & 1];
#pragma unroll 2
        for (int ct = 0; ct < TILE / 16; ++ct) {
            half8 bh = buf[(0 * 4 + quad) * LSTRIDE + ct * 16 + lc];
            half8 bm = buf[(1 * 4 + quad) * LSTRIDE + ct * 16 + lc];
            const int kk = kbase + kt * TILE + ct * 16 + lc;
#pragma unroll
            for (int qt = 0; qt < 4; ++qt) {
                floatx4 acc = __builtin_amdgcn_mfma_f32_16x16x32_f16(ah4[qt], bh, z4, 0, 0, 0);
                acc = __builtin_amdgcn_mfma_f32_16x16x32_f16(ah[qt], bm, acc, 0, 0, 0);
                acc = __builtin_amdgcn_mfma_f32_16x16x32_f16(am[qt], bh, acc, 0, 0, 0);
#pragma unroll
                for (int r = 0; r < 4; ++r) {
                    float d = acc[r];
                    if (d > best[qt * 4 + r]) { best[qt * 4 + r] = d; bk[qt * 4 + r] = kk; }
                }
            }
        }
        __syncthreads();   // drains DMA (vmcnt0) + frees computed buffer
    }

    // ---- epilogue: pack (scaled dot, k), reduce over 16 cols, coherent store ----
#pragma unroll
    for (int i = 0; i < 16; ++i) {
        unsigned ub = __float_as_uint(best[i]);
        ub = (ub & 0x80000000u) ? ~ub : (ub | 0x80000000u);
        unsigned long long key = ((unsigned long long)ub << 32) | (unsigned)(~bk[i]);
#pragma unroll
        for (int msk = 1; msk <= 8; msk <<= 1) {
            unsigned long long o = __shfl_xor(key, msk, 64);
            key = (o > key) ? o : key;
        }
        if (lc == 0) {
            int qt = i >> 2, r = i & 3;
            int q = qbase + qt * 16 + quad * 4 + r;   // C row = quad*4 + reg
            __hip_atomic_store(&keys16[kc * NQ + q], key,
                               __ATOMIC_RELAXED, __HIP_MEMORY_SCOPE_AGENT);
        }
    }
}

// K2: finalize — R8's proven version. 1 thread/query, 256 blocks x 128.
__global__ __launch_bounds__(128) void finalize_kernel(const float* __restrict__ z,
                                                       const float* __restrict__ e,
                                                       const unsigned long long* __restrict__ keys16,
                                                       unsigned* __restrict__ usage,
                                                       float* __restrict__ loss_acc,
                                                       float* __restrict__ out) {
    int n = blockIdx.x * 128 + threadIdx.x;        // 0..NQ-1
    int b  = n >> 10;
    int hw = n & 1023;
    const float* zb = z + b * (DIM * 1024) + hw;

    float q[DIM];
    float ss = 0.f;
#pragma unroll
    for (int d = 0; d < DIM; ++d) {
        q[d] = zb[d * 1024];
        ss = fmaf(q[d], q[d], ss);
    }
    float inv = 1.f / fmaxf(sqrtf(ss), 1e-12f);
#pragma unroll
    for (int d = 0; d < DIM; ++d) q[d] *= inv;

    unsigned long long bestkey = 0ull;
#pragma unroll
    for (int c = 0; c < KSPL; ++c) {
        unsigned long long k16 = __hip_atomic_load(&keys16[c * NQ + n],
                                                   __ATOMIC_RELAXED,
                                                   __HIP_MEMORY_SCOPE_AGENT);
        bestkey = (k16 > bestkey) ? k16 : bestkey;
    }
    int idx = (int)(~(unsigned)(bestkey & 0xFFFFFFFFull));

    atomicAdd(&usage[idx], 1u);

    // gather winner row, normalize locally, write straight-through + loss
    float wv[DIM];
    float ss2 = 0.f;
    const float4* er = (const float4*)(e + idx * DIM);
#pragma unroll
    for (int d8 = 0; d8 < 8; ++d8) {
        float4 t4 = er[d8];
        wv[d8*4+0] = t4.x; wv[d8*4+1] = t4.y; wv[d8*4+2] = t4.z; wv[d8*4+3] = t4.w;
        ss2 += t4.x*t4.x + t4.y*t4.y + t4.z*t4.z + t4.w*t4.w;
    }
    float inv2 = 1.f / fmaxf(sqrtf(ss2), 1e-12f);

    float lsum = 0.f;
    float* outb = out + b * (DIM * 1024) + hw;
#pragma unroll
    for (int d = 0; d < DIM; ++d) {
        float zq = wv[d] * inv2;
        float diff = zq - q[d];
        lsum = fmaf(diff, diff, lsum);
        outb[d * 1024] = q[d] + (zq - q[d]);   // faithful to zn + sg(z_q - zn)
    }
    out[IDX_OFF + n] = (float)idx;

    // block-level loss reduction: wave shfl -> LDS -> one atomic per block
#pragma unroll
    for (int off = 32; off > 0; off >>= 1)
        lsum += __shfl_down(lsum, off, 64);
    __shared__ float wsum[2];
    if ((threadIdx.x & 63) == 0) wsum[threadIdx.x >> 6] = lsum;
    __syncthreads();
    if (threadIdx.x == 0)
        atomicAdd(loss_acc, wsum[0] + wsum[1]);
}

// K3: scalars. Stream-ordered after finalize.
__global__ __launch_bounds__(256) void scalar_kernel(const unsigned* __restrict__ usage,
                                                     const float* __restrict__ loss_acc,
                                                     float* __restrict__ out) {
    __shared__ double sm[256];
    int t = threadIdx.x;
    double local = 0.0;
    const float denom = 32768.8192f;   // sum(usage)+K*eps; sum(usage)==NQ
    for (int k = t; k < N_EMBED; k += 256) {
        unsigned c = __hip_atomic_load(&usage[k], __ATOMIC_RELAXED,
                                       __HIP_MEMORY_SCOPE_AGENT);
        float p = ((float)c + 1e-4f) / denom;
        local += (double)(-(p * logf(p)));
    }
    sm[t] = local;
    __syncthreads();
    for (int s = 128; s > 0; s >>= 1) {
        if (t < s) sm[t] += sm[t + s];
        __syncthreads();
    }
    if (t == 0) {
        float la = __hip_atomic_load(loss_acc, __ATOMIC_RELAXED,
                                     __HIP_MEMORY_SCOPE_AGENT);
        out[LOSS_OFF] = (float)(1.25 * (double)la / 32768.0);  // (beta+1)*mean
        out[ENT_OFF]  = (float)sm[0];
    }
}

// ---------------------------------------------------------------------------
extern "C" void kernel_launch(void* const* d_in, const int* in_sizes, int n_in,
                              void* d_out, int out_size, void* d_ws, size_t ws_size,
                              hipStream_t stream) {
    const float* z   = (const float*)d_in[0];   // (32, 32, 32, 32) bchw
    const float* emb = (const float*)d_in[1];   // (8192, 32)
    float* out = (float*)d_out;

    char* ws = (char*)d_ws;
    unsigned long long* keys16 = (unsigned long long*)ws;                    // 2 MiB @ 0
    half8* prep                = (half8*)(ws + (2 << 20));                   // 1 MiB
    unsigned* usage            = (unsigned*)(ws + (3 << 20));                // 32 KiB
    float* loss_acc            = (float*)(ws + (3 << 20) + 32768);

    prep_kernel<<<(N_EMBED * 4) / 256, 256, 0, stream>>>(emb, prep, usage, loss_acc);
    score_kernel<<<NQG * KSPL, 512, 0, stream>>>(z, prep, keys16);
    finalize_kernel<<<NQ / 128, 128, 0, stream>>>(z, emb, keys16, usage,
                                                  loss_acc, out);
    scalar_kernel<<<1, 256, 0, stream>>>(usage, loss_acc, out);
}